// Round 3
// baseline (62.961 us; speedup 1.0000x reference)
//
#include <hip/hip_runtime.h>
#include <hip/hip_bf16.h>
#include <stdint.h>

#define D_DIM 2048
#define B_DIM 4096
#define BMT 128                       // output tile M = N
#define BKT 64                        // K step (elements)
#define NKSTEPS (B_DIM / BKT)         // 64 total K-steps
#define NTILE (D_DIM / BMT)           // 16
#define NPAIR ((NTILE * (NTILE + 1)) / 2)  // 136 upper-triangle tile pairs
// Non-uniform K-split: 72 pairs x 8 + 64 pairs x 7 = 1024 blocks = 4/CU x 256 CU
#define P8 72
#define GRAM_BLOCKS (P8 * 8 + (NPAIR - P8) * 7)   // 1024
#define MWORDS (D_DIM / 64)           // 32 mask words per row
#define NT32 (D_DIM / 64)             // 32 row-blocks for mask kernel
#define MPAIR ((NT32 * (NT32 + 1)) / 2)  // 528 upper mask block pairs

typedef __attribute__((ext_vector_type(8))) short bf16x8;
typedef __attribute__((ext_vector_type(4))) float f32x4;

__device__ __forceinline__ void gload16(const void* g, void* lds) {
    __builtin_amdgcn_global_load_lds((__attribute__((address_space(1))) void*)g,
                                     (__attribute__((address_space(3))) void*)lds,
                                     16, 0, 0);
}

__device__ __forceinline__ unsigned short f2bf(float f) {
    __hip_bfloat16 h = __float2bfloat16(f);
    return *reinterpret_cast<unsigned short*>(&h);
}

// X (B_DIM x D_DIM, f32, row-major) -> XT (D_DIM x B_DIM, bf16, row-major), XT[i][k] = X[k][i]
// Also zero-inits gsum/gcnt (block (0,0)); stream order guarantees visibility to later dispatches.
__global__ __launch_bounds__(256) void transpose_bf16_kernel(
    const float* __restrict__ X, unsigned short* __restrict__ XT,
    float* gsum, int* gcnt)
{
    __shared__ float tile[64][65];
    const int tid = threadIdx.x;
    const int i0 = blockIdx.x * 64;   // column block of X = row block of XT
    const int k0 = blockIdx.y * 64;   // row block of X
    if (blockIdx.x == 0 && blockIdx.y == 0 && tid == 0) { *gsum = 0.f; *gcnt = 0; }

    // float4 loads: 16 B/lane, fully coalesced
    const int c4 = tid & 15;          // float4 index within 64-float row
    const int rr = tid >> 4;          // 0..15
    #pragma unroll
    for (int p = 0; p < 4; ++p) {
        const int kr = p * 16 + rr;
        const float4 v = *reinterpret_cast<const float4*>(
            &X[(size_t)(k0 + kr) * D_DIM + i0 + c4 * 4]);
        tile[kr][c4 * 4 + 0] = v.x;
        tile[kr][c4 * 4 + 1] = v.y;
        tile[kr][c4 * 4 + 2] = v.z;
        tile[kr][c4 * 4 + 3] = v.w;
    }
    __syncthreads();

    const int ir16 = tid >> 4;        // 0..15
    const int kq   = tid & 15;        // 0..15
    #pragma unroll
    for (int pi = 0; pi < 4; ++pi) {
        const int ir = pi * 16 + ir16;
        const int kc = kq * 4;
        ushort4 v;
        v.x = f2bf(tile[kc + 0][ir]);
        v.y = f2bf(tile[kc + 1][ir]);
        v.z = f2bf(tile[kc + 2][ir]);
        v.w = f2bf(tile[kc + 3][ir]);
        *reinterpret_cast<ushort4*>(XT + (size_t)(i0 + ir) * B_DIM + k0 + kc) = v;
    }
}

// Packed upper-triangle mask over 64x64 block pairs (bi<=bj only — each ddi tile read once).
// bit (i,j) = (i<j) && (ddi[i][j]>0 || ddi[j][i]>0); words below the diagonal stay UNWRITTEN
// (gram epilogue guards them). Also accumulates total edge count.
__global__ __launch_bounds__(256) void mask_kernel(
    const float* __restrict__ ddi,
    unsigned long long* __restrict__ mask64,
    int* __restrict__ gcnt)
{
    __shared__ float tileT[64][65];   // ddi[c0+k][r0+i] (the (bj,bi) tile)
    __shared__ int redi[4];
    const int tid = threadIdx.x;

    int bi = 0, rem = blockIdx.x;
    while (rem >= NT32 - bi) { rem -= NT32 - bi; ++bi; }
    const int bj = bi + rem;
    const int r0 = bi * 64;
    const int c0 = bj * 64;

    // load transposed-access tile with float4
    const int c4 = tid & 15;
    const int rr = tid >> 4;
    #pragma unroll
    for (int p = 0; p < 4; ++p) {
        const int kr = p * 16 + rr;
        const float4 v = *reinterpret_cast<const float4*>(
            &ddi[(size_t)(c0 + kr) * D_DIM + r0 + c4 * 4]);
        tileT[kr][c4 * 4 + 0] = v.x;
        tileT[kr][c4 * 4 + 1] = v.y;
        tileT[kr][c4 * 4 + 2] = v.z;
        tileT[kr][c4 * 4 + 3] = v.w;
    }
    __syncthreads();

    const int lane = tid & 63;
    const int w    = tid >> 6;
    int cnt = 0;
    #pragma unroll
    for (int rr2 = 0; rr2 < 16; ++rr2) {
        const int li = w * 16 + rr2;
        const int gi = r0 + li;
        const int gj = c0 + lane;
        const float a  = ddi[(size_t)gi * D_DIM + c0 + lane];  // coalesced row read
        const float at = tileT[lane][li];                      // ddi[gj][gi]
        const bool bit = (gi < gj) && (a > 0.f || at > 0.f);
        const unsigned long long word = __ballot(bit);
        if (lane == 0) mask64[(size_t)gi * MWORDS + bj] = word;
        cnt += bit ? 1 : 0;
    }
    #pragma unroll
    for (int off = 32; off > 0; off >>= 1) cnt += __shfl_down(cnt, off, 64);
    if (lane == 0) redi[w] = cnt;
    __syncthreads();
    if (tid == 0) atomicAdd(gcnt, redi[0] + redi[1] + redi[2] + redi[3]);
}

// C = XT_panel_i · XT_panel_j^T (Gram), fused bitmask + reduce.
// m97 structure: 128x128 tile, BK=64, 4 waves (2x2 of 64x64), single-buffered LDS (32 KiB
// -> 4 blocks/CU, 16 waves/CU), 2 barriers per K-step. Implicit cross-block overlap (m114)
// does the pipelining. Grid = exactly 1024 blocks (one full residency round, no tail).
__global__ __launch_bounds__(256) void gram_masked_kernel(
    const unsigned short* __restrict__ XT,
    const unsigned long long* __restrict__ mask64,
    float* __restrict__ gsum)
{
    __shared__ unsigned short lsA[BMT * BKT];   // 16 KiB
    __shared__ unsigned short lsB[BMT * BKT];   // 16 KiB
    __shared__ float redf[4];

    const int tid  = threadIdx.x;
    const int lane = tid & 63;
    const int w    = tid >> 6;        // wave 0..3
    const int wr   = w >> 1, wc = w & 1;
    const int m16  = lane & 15;
    const int g    = lane >> 4;       // k-group 0..3

    // Non-uniform K-split decode: first 72 pairs have 8 splits, rest 7.
    const int bid = blockIdx.x;
    int pair, s, ns;
    if (bid < P8 * 8) { pair = bid >> 3; s = bid & 7; ns = 8; }
    else { const int t = bid - P8 * 8; pair = P8 + t / 7; s = t % 7; ns = 7; }

    int ti = 0, rem = pair;
    while (rem >= NTILE - ti) { rem -= NTILE - ti; ++ti; }
    const int tj = ti + rem;
    const int i0 = ti * BMT, j0 = tj * BMT;

    const int ks0 = (NKSTEPS * s) / ns;       // K-step range [ks0, ks1)
    const int ks1 = (NKSTEPS * (s + 1)) / ns;
    const int nkt = ks1 - ks0;
    const int kbase = ks0 * BKT;

    f32x4 acc[4][4];
    #pragma unroll
    for (int a = 0; a < 4; ++a)
        #pragma unroll
        for (int b = 0; b < 4; ++b)
            acc[a][b] = (f32x4){0.f, 0.f, 0.f, 0.f};

    // Staging: chunk = p*256 + tid; 16B chunks, row = chunk/8, within-row 16B idx = chunk%8.
    // Linear LDS dest (global_load_lds requirement) + inverse-swizzled global source [rule #21]:
    // linear slot (row,c8) receives global chunk (row, c8 ^ (row&7)).
    size_t gaoff[4], gboff[4];
    #pragma unroll
    for (int p = 0; p < 4; ++p) {
        const int chunk = p * 256 + tid;
        const int row = chunk >> 3;
        const int sc8 = (chunk & 7) ^ (row & 7);
        gaoff[p] = (size_t)(i0 + row) * B_DIM + kbase + sc8 * 8;
        gboff[p] = (size_t)(j0 + row) * B_DIM + kbase + sc8 * 8;
    }
    char* lbaseA = (char*)lsA + (size_t)w * 1024;   // wave-uniform segment base
    char* lbaseB = (char*)lsB + (size_t)w * 1024;

    for (int kt = 0; kt < nkt; ++kt) {
        const int koff = kt * BKT;
        #pragma unroll
        for (int p = 0; p < 4; ++p) {
            gload16(XT + gaoff[p] + koff, lbaseA + p * 4096);
            gload16(XT + gboff[p] + koff, lbaseB + p * 4096);
        }
        __syncthreads();   // drains vmcnt (LDS tiles ready)
        #pragma unroll
        for (int kk = 0; kk < 2; ++kk) {
            bf16x8 aF[4], bF[4];
            #pragma unroll
            for (int f = 0; f < 4; ++f) {
                const int rowA = wr * 64 + f * 16 + m16;
                const int cA = (kk * 4 + g) ^ (rowA & 7);   // swizzled read
                aF[f] = *reinterpret_cast<const bf16x8*>((const char*)lsA + rowA * 128 + cA * 16);
                const int rowB = wc * 64 + f * 16 + m16;
                const int cB = (kk * 4 + g) ^ (rowB & 7);
                bF[f] = *reinterpret_cast<const bf16x8*>((const char*)lsB + rowB * 128 + cB * 16);
            }
            #pragma unroll
            for (int fi = 0; fi < 4; ++fi)
                #pragma unroll
                for (int fj = 0; fj < 4; ++fj)
                    acc[fi][fj] = __builtin_amdgcn_mfma_f32_16x16x32_bf16(
                        aF[fi], bF[fj], acc[fi][fj], 0, 0, 0);
        }
        __syncthreads();   // all waves done reading before next-stage overwrite
    }

    // Fused epilogue: masked sum from packed bits (mask encodes i<j already).
    // C/D layout: col = lane&15, row = (lane>>4)*4 + reg  [m89/m91 verified]
    // Guard: mask words entirely below the diagonal are unwritten (0xAA poison) — skip them.
    float lsum = 0.f;
    const int jb = (j0 + wc * 64) >> 6;   // single mask word column per lane
    #pragma unroll
    for (int fi = 0; fi < 4; ++fi) {
        #pragma unroll
        for (int r = 0; r < 4; ++r) {
            const int i = i0 + wr * 64 + fi * 16 + g * 4 + r;
            unsigned long long wword = 0ull;
            if (jb * 64 + 63 > i) wword = mask64[(size_t)i * MWORDS + jb];
            #pragma unroll
            for (int fj = 0; fj < 4; ++fj) {
                if ((wword >> (fj * 16 + m16)) & 1ull) lsum += acc[fi][fj][r];
            }
        }
    }
    #pragma unroll
    for (int off = 32; off > 0; off >>= 1) lsum += __shfl_down(lsum, off, 64);
    if (lane == 0) redf[w] = lsum;
    __syncthreads();
    if (tid == 0) atomicAdd(gsum, redf[0] + redf[1] + redf[2] + redf[3]);
}

__global__ void finalize_kernel(const float* gsum, const int* gcnt, float* out) {
    out[0] = gsum[0] / ((float)B_DIM * fmaxf((float)gcnt[0], 1.0f));
}

extern "C" void kernel_launch(void* const* d_in, const int* in_sizes, int n_in,
                              void* d_out, int out_size, void* d_ws, size_t ws_size,
                              hipStream_t stream) {
    const float* X   = (const float*)d_in[0];   // drug_probs (B_DIM x D_DIM)
    const float* ddi = (const float*)d_in[1];   // ddi_matrix (D_DIM x D_DIM)
    float* out = (float*)d_out;

    const size_t XT_BYTES   = (size_t)D_DIM * B_DIM * sizeof(unsigned short);      // 16 MiB
    const size_t MASK_BYTES = (size_t)D_DIM * MWORDS * sizeof(unsigned long long); // 512 KiB
    if (ws_size < XT_BYTES + MASK_BYTES + 16) return;

    unsigned short* XT = (unsigned short*)d_ws;
    unsigned long long* mask64 = (unsigned long long*)((char*)d_ws + XT_BYTES);
    float* gsum = (float*)((char*)d_ws + XT_BYTES + MASK_BYTES);
    int*   gcnt = (int*)((char*)d_ws + XT_BYTES + MASK_BYTES + sizeof(float));

    transpose_bf16_kernel<<<dim3(D_DIM / 64, B_DIM / 64), 256, 0, stream>>>(X, XT, gsum, gcnt);
    mask_kernel<<<MPAIR, 256, 0, stream>>>(ddi, mask64, gcnt);
    gram_masked_kernel<<<GRAM_BLOCKS, 256, 0, stream>>>(XT, mask64, gsum);
    finalize_kernel<<<1, 1, 0, stream>>>(gsum, gcnt, out);
}

// Round 4
// 49.275 us; speedup vs baseline: 1.2778x; 1.2778x over previous
//
#include <hip/hip_runtime.h>
#include <stdint.h>

#define D_DIM 2048
#define B_DIM 4096
#define BMT 128                       // output tile M = N
#define BKB 128                       // K step in BYTES (= 128 fp8 elements)
#define NKS (B_DIM / 128)             // 32 K-steps total
#define NSPL 6                        // K-splits per pair
#define NTILE (D_DIM / BMT)           // 16
#define NPAIR ((NTILE * (NTILE + 1)) / 2)  // 136 upper-triangle tile pairs
#define GRAM_BLOCKS (NPAIR * NSPL)    // 816 = 8 XCDs x 102
#define MWORDS (D_DIM / 64)           // 32 mask words per row
#define NT32 (D_DIM / 64)             // 32 row-blocks for mask part
#define MPAIR ((NT32 * (NT32 + 1)) / 2)  // 528 upper mask block pairs
#define TP_BLOCKS ((D_DIM / 64) * (B_DIM / 64))  // 2048 transpose blocks

typedef __attribute__((ext_vector_type(4))) float f32x4;

__device__ __forceinline__ void gload16(const void* g, void* lds) {
    __builtin_amdgcn_global_load_lds((__attribute__((address_space(1))) void*)g,
                                     (__attribute__((address_space(3))) void*)lds,
                                     16, 0, 0);
}

// Fused prep: transpose X -> fp8 XT (blocks [0, TP_BLOCKS)) and build the packed
// upper-triangle mask + per-block edge counts (blocks [TP_BLOCKS, TP_BLOCKS+MPAIR)).
// Counts go to partials[] (no atomic -> no init race); gsum zeroed by block 0.
__global__ __launch_bounds__(256) void prep_kernel(
    const float* __restrict__ X, const float* __restrict__ ddi,
    unsigned char* __restrict__ XT8, unsigned long long* __restrict__ mask64,
    int* __restrict__ partials, float* __restrict__ gsum)
{
    __shared__ float tile[64][65];
    __shared__ int redi[4];
    const int tid = threadIdx.x;

    if (blockIdx.x < TP_BLOCKS) {
        // ---- transpose + f32->fp8(e4m3, RNE) ----
        if (blockIdx.x == 0 && tid == 0) *gsum = 0.f;
        const int i0 = (blockIdx.x & 31) * 64;   // D/64 = 32 column blocks of X
        const int k0 = (blockIdx.x >> 5) * 64;   // row block of X

        const int c4 = tid & 15;
        const int rr = tid >> 4;
        #pragma unroll
        for (int p = 0; p < 4; ++p) {
            const int kr = p * 16 + rr;
            const float4 v = *reinterpret_cast<const float4*>(
                &X[(size_t)(k0 + kr) * D_DIM + i0 + c4 * 4]);
            tile[kr][c4 * 4 + 0] = v.x;
            tile[kr][c4 * 4 + 1] = v.y;
            tile[kr][c4 * 4 + 2] = v.z;
            tile[kr][c4 * 4 + 3] = v.w;
        }
        __syncthreads();

        const int ir16 = tid >> 4;
        const int kq   = tid & 15;
        #pragma unroll
        for (int pi = 0; pi < 4; ++pi) {
            const int ir = pi * 16 + ir16;
            const int kc = kq * 4;
            int pk = __builtin_amdgcn_cvt_pk_fp8_f32(tile[kc + 0][ir], tile[kc + 1][ir], 0, false);
            pk     = __builtin_amdgcn_cvt_pk_fp8_f32(tile[kc + 2][ir], tile[kc + 3][ir], pk, true);
            *reinterpret_cast<int*>(XT8 + (size_t)(i0 + ir) * B_DIM + k0 + kc) = pk;
        }
    } else {
        // ---- mask: bit (i,j) = (i<j) && (ddi[i][j]>0 || ddi[j][i]>0), 64x64 block pairs bi<=bj ----
        const int mb = blockIdx.x - TP_BLOCKS;
        int bi = 0, rem = mb;
        while (rem >= NT32 - bi) { rem -= NT32 - bi; ++bi; }
        const int bj = bi + rem;
        const int r0 = bi * 64;
        const int c0 = bj * 64;

        const int c4 = tid & 15;
        const int rr = tid >> 4;
        #pragma unroll
        for (int p = 0; p < 4; ++p) {
            const int kr = p * 16 + rr;
            const float4 v = *reinterpret_cast<const float4*>(
                &ddi[(size_t)(c0 + kr) * D_DIM + r0 + c4 * 4]);
            tile[kr][c4 * 4 + 0] = v.x;
            tile[kr][c4 * 4 + 1] = v.y;
            tile[kr][c4 * 4 + 2] = v.z;
            tile[kr][c4 * 4 + 3] = v.w;
        }
        __syncthreads();

        const int lane = tid & 63;
        const int w    = tid >> 6;
        int cnt = 0;
        #pragma unroll
        for (int rr2 = 0; rr2 < 16; ++rr2) {
            const int li = w * 16 + rr2;
            const int gi = r0 + li;
            const int gj = c0 + lane;
            const float a  = ddi[(size_t)gi * D_DIM + c0 + lane];  // coalesced row read
            const float at = tile[lane][li];                       // ddi[gj][gi]
            const bool bit = (gi < gj) && (a > 0.f || at > 0.f);
            const unsigned long long word = __ballot(bit);
            if (lane == 0) mask64[(size_t)gi * MWORDS + bj] = word;
            cnt += bit ? 1 : 0;
        }
        #pragma unroll
        for (int off = 32; off > 0; off >>= 1) cnt += __shfl_down(cnt, off, 64);
        if (lane == 0) redi[w] = cnt;
        __syncthreads();
        if (tid == 0) partials[mb] = redi[0] + redi[1] + redi[2] + redi[3];
    }
}

// Gram = XT8_panel_i · XT8_panel_j^T in fp8 e4m3 (f32 accum), fused bitmask + reduce.
// 128x128 tile, BK=128 fp8 (same 128 B/row geometry as bf16-BK64), 4 waves (2x2 of 64x64),
// single-buffered LDS 32 KiB, 2 barriers/K-step (m97 structure), gload16 staging with
// (row&7) 16B-granule XOR swizzle [rule #21]; b64 frag reads are 2-way = free (m136).
// Grid 816 = 136 pairs x 6 K-splits, XCD-chunked bijective swizzle (816 = 8 x 102).
__global__ __launch_bounds__(256) void gram_masked_kernel(
    const unsigned char* __restrict__ XT8,
    const unsigned long long* __restrict__ mask64,
    float* __restrict__ gsum)
{
    __shared__ __align__(16) unsigned char lsA[BMT * BKB];   // 16 KiB
    __shared__ __align__(16) unsigned char lsB[BMT * BKB];   // 16 KiB
    __shared__ float redf[4];

    const int tid  = threadIdx.x;
    const int lane = tid & 63;
    const int w    = tid >> 6;        // wave 0..3
    const int wr   = w >> 1, wc = w & 1;
    const int m16  = lane & 15;
    const int g    = lane >> 4;       // k-group 0..3

    // XCD-chunked ordering: XCD (bid%8) processes logical chunk [x*102, (x+1)*102):
    // contiguous ti-range -> A-panels stay in that XCD's L2 (fp8 panel = 0.5 MiB).
    const int bid = blockIdx.x;
    const int logical = (bid & 7) * (GRAM_BLOCKS / 8) + (bid >> 3);
    const int pair = logical / NSPL;          // ti-major pair order
    const int s    = logical % NSPL;

    int ti = 0, rem = pair;
    while (rem >= NTILE - ti) { rem -= NTILE - ti; ++ti; }
    const int tj = ti + rem;
    const int i0 = ti * BMT, j0 = tj * BMT;

    const int ks0 = (NKS * s) / NSPL;         // K-step range [ks0, ks1), 5-6 steps
    const int ks1 = (NKS * (s + 1)) / NSPL;
    const int nkt = ks1 - ks0;
    const int kbase = ks0 * BKB;              // byte offset into the 4096-byte K row

    f32x4 acc[4][4];
    #pragma unroll
    for (int a = 0; a < 4; ++a)
        #pragma unroll
        for (int b = 0; b < 4; ++b)
            acc[a][b] = (f32x4){0.f, 0.f, 0.f, 0.f};

    // Staging: chunk = p*256 + tid; 16B granules, row = chunk/8 (8 granules per 128 B row).
    // Linear LDS dest + inverse-swizzled global source: slot (row,c) gets granule (row, c^(row&7)).
    size_t gaoff[4], gboff[4];
    #pragma unroll
    for (int p = 0; p < 4; ++p) {
        const int chunk = p * 256 + tid;
        const int row = chunk >> 3;
        const int sc = (chunk & 7) ^ (row & 7);
        gaoff[p] = (size_t)(i0 + row) * B_DIM + kbase + sc * 16;
        gboff[p] = (size_t)(j0 + row) * B_DIM + kbase + sc * 16;
    }
    char* lbaseA = (char*)lsA + (size_t)w * 1024;   // wave-uniform segment base
    char* lbaseB = (char*)lsB + (size_t)w * 1024;

    for (int kt = 0; kt < nkt; ++kt) {
        const int koff = kt * BKB;
        #pragma unroll
        for (int p = 0; p < 4; ++p) {
            gload16(XT8 + gaoff[p] + koff, lbaseA + p * 4096);
            gload16(XT8 + gboff[p] + koff, lbaseB + p * 4096);
        }
        __syncthreads();   // drains vmcnt (LDS tiles ready)
        #pragma unroll
        for (int kk = 0; kk < 4; ++kk) {        // 4 x K=32 fp8 MFMA per K-step
            long aF[4], bF[4];
            const int c16 = kk * 2 + (g >> 1);  // 16B granule holding this lane's 8 k-bytes
            const int h8  = (g & 1) * 8;
            #pragma unroll
            for (int f = 0; f < 4; ++f) {
                const int rowA = wr * 64 + f * 16 + m16;
                aF[f] = *reinterpret_cast<const long*>(
                    lsA + rowA * BKB + ((c16 ^ (rowA & 7)) << 4) + h8);
                const int rowB = wc * 64 + f * 16 + m16;
                bF[f] = *reinterpret_cast<const long*>(
                    lsB + rowB * BKB + ((c16 ^ (rowB & 7)) << 4) + h8);
            }
            #pragma unroll
            for (int fi = 0; fi < 4; ++fi)
                #pragma unroll
                for (int fj = 0; fj < 4; ++fj)
                    acc[fi][fj] = __builtin_amdgcn_mfma_f32_16x16x32_fp8_fp8(
                        aF[fi], bF[fj], acc[fi][fj], 0, 0, 0);
        }
        __syncthreads();   // all waves done reading before next-stage overwrite
    }

    // Fused epilogue: masked sum from packed bits (mask encodes i<j already).
    // C/D layout: col = lane&15, row = (lane>>4)*4 + reg  [m89/m91; dtype-independent]
    // Guard: words entirely below the diagonal are unwritten (poison) — skip them.
    float lsum = 0.f;
    const int jb = (j0 + wc * 64) >> 6;
    #pragma unroll
    for (int fi = 0; fi < 4; ++fi) {
        #pragma unroll
        for (int r = 0; r < 4; ++r) {
            const int i = i0 + wr * 64 + fi * 16 + g * 4 + r;
            unsigned long long wword = 0ull;
            if (jb * 64 + 63 > i) wword = mask64[(size_t)i * MWORDS + jb];
            #pragma unroll
            for (int fj = 0; fj < 4; ++fj) {
                if ((wword >> (fj * 16 + m16)) & 1ull) lsum += acc[fi][fj][r];
            }
        }
    }
    #pragma unroll
    for (int off = 32; off > 0; off >>= 1) lsum += __shfl_down(lsum, off, 64);
    if (lane == 0) redf[w] = lsum;
    __syncthreads();
    if (tid == 0) atomicAdd(gsum, redf[0] + redf[1] + redf[2] + redf[3]);
}

__global__ __launch_bounds__(256) void finalize_kernel(
    const float* __restrict__ gsum, const int* __restrict__ partials,
    float* __restrict__ out)
{
    __shared__ int redi[4];
    const int tid = threadIdx.x;
    int s = 0;
    for (int i = tid; i < MPAIR; i += 256) s += partials[i];
    #pragma unroll
    for (int off = 32; off > 0; off >>= 1) s += __shfl_down(s, off, 64);
    const int lane = tid & 63, w = tid >> 6;
    if (lane == 0) redi[w] = s;
    __syncthreads();
    if (tid == 0) {
        const int cnt = redi[0] + redi[1] + redi[2] + redi[3];
        out[0] = gsum[0] / ((float)B_DIM * fmaxf((float)cnt, 1.0f));
    }
}

extern "C" void kernel_launch(void* const* d_in, const int* in_sizes, int n_in,
                              void* d_out, int out_size, void* d_ws, size_t ws_size,
                              hipStream_t stream) {
    const float* X   = (const float*)d_in[0];   // drug_probs (B_DIM x D_DIM)
    const float* ddi = (const float*)d_in[1];   // ddi_matrix (D_DIM x D_DIM)
    float* out = (float*)d_out;

    const size_t XT_BYTES   = (size_t)D_DIM * B_DIM;                                // 8 MiB fp8
    const size_t MASK_BYTES = (size_t)D_DIM * MWORDS * sizeof(unsigned long long);  // 512 KiB
    const size_t PART_BYTES = (size_t)MPAIR * sizeof(int);
    if (ws_size < XT_BYTES + MASK_BYTES + PART_BYTES + 16) return;

    unsigned char* XT8 = (unsigned char*)d_ws;
    unsigned long long* mask64 = (unsigned long long*)((char*)d_ws + XT_BYTES);
    int*   partials = (int*)((char*)d_ws + XT_BYTES + MASK_BYTES);
    float* gsum     = (float*)((char*)d_ws + XT_BYTES + MASK_BYTES + PART_BYTES);

    prep_kernel<<<TP_BLOCKS + MPAIR, 256, 0, stream>>>(X, ddi, XT8, mask64, partials, gsum);
    gram_masked_kernel<<<GRAM_BLOCKS, 256, 0, stream>>>(XT8, mask64, gsum);
    finalize_kernel<<<1, 256, 0, stream>>>(gsum, partials, out);
}

// Round 5
// 44.323 us; speedup vs baseline: 1.4205x; 1.1117x over previous
//
#include <hip/hip_runtime.h>
#include <stdint.h>

#define D_DIM 2048
#define B_DIM 4096
#define BMT 128                       // output tile M = N
#define BKB 128                       // K step in BYTES (= 128 fp8 elements)
#define NKS (B_DIM / 128)             // 32 K-steps total
#define NSPL 6                        // K-splits per pair
#define NTILE (D_DIM / BMT)           // 16
#define NPAIR ((NTILE * (NTILE + 1)) / 2)  // 136 upper-triangle tile pairs
#define GRAM_BLOCKS (NPAIR * NSPL)    // 816 = 8 XCDs x 102
#define MWORDS (D_DIM / 64)           // 32 mask words per row
#define NT32 (D_DIM / 64)             // 32 row-blocks for mask part
#define MPAIR ((NT32 * (NT32 + 1)) / 2)  // 528 upper mask block pairs
#define TP_BLOCKS ((D_DIM / 64) * (B_DIM / 64))  // 2048 transpose blocks

typedef __attribute__((ext_vector_type(4))) float f32x4;
typedef __attribute__((ext_vector_type(4))) int   i32x4;
typedef __attribute__((ext_vector_type(8))) int   i32x8;

__device__ __forceinline__ void gload16(const void* g, void* lds) {
    __builtin_amdgcn_global_load_lds((__attribute__((address_space(1))) void*)g,
                                     (__attribute__((address_space(3))) void*)lds,
                                     16, 0, 0);
}

// Fused prep: transpose X -> fp8 XT (blocks [0, TP_BLOCKS)) and build the packed
// upper-triangle mask + per-block edge counts (blocks [TP_BLOCKS, TP_BLOCKS+MPAIR)).
// Counts go to partials[] (no atomic -> no init race); gsum zeroed by block 0.
__global__ __launch_bounds__(256) void prep_kernel(
    const float* __restrict__ X, const float* __restrict__ ddi,
    unsigned char* __restrict__ XT8, unsigned long long* __restrict__ mask64,
    int* __restrict__ partials, float* __restrict__ gsum)
{
    __shared__ float tile[64][65];
    __shared__ int redi[4];
    const int tid = threadIdx.x;

    if (blockIdx.x < TP_BLOCKS) {
        // ---- transpose + f32->fp8(e4m3, RNE) ----
        if (blockIdx.x == 0 && tid == 0) *gsum = 0.f;
        const int i0 = (blockIdx.x & 31) * 64;   // D/64 = 32 column blocks of X
        const int k0 = (blockIdx.x >> 5) * 64;   // row block of X

        const int c4 = tid & 15;
        const int rr = tid >> 4;
        #pragma unroll
        for (int p = 0; p < 4; ++p) {
            const int kr = p * 16 + rr;
            const float4 v = *reinterpret_cast<const float4*>(
                &X[(size_t)(k0 + kr) * D_DIM + i0 + c4 * 4]);
            tile[kr][c4 * 4 + 0] = v.x;
            tile[kr][c4 * 4 + 1] = v.y;
            tile[kr][c4 * 4 + 2] = v.z;
            tile[kr][c4 * 4 + 3] = v.w;
        }
        __syncthreads();

        const int ir16 = tid >> 4;
        const int kq   = tid & 15;
        #pragma unroll
        for (int pi = 0; pi < 4; ++pi) {
            const int ir = pi * 16 + ir16;
            const int kc = kq * 4;
            int pk = __builtin_amdgcn_cvt_pk_fp8_f32(tile[kc + 0][ir], tile[kc + 1][ir], 0, false);
            pk     = __builtin_amdgcn_cvt_pk_fp8_f32(tile[kc + 2][ir], tile[kc + 3][ir], pk, true);
            *reinterpret_cast<int*>(XT8 + (size_t)(i0 + ir) * B_DIM + k0 + kc) = pk;
        }
    } else {
        // ---- mask: bit (i,j) = (i<j) && (ddi[i][j]>0 || ddi[j][i]>0), 64x64 block pairs bi<=bj ----
        const int mb = blockIdx.x - TP_BLOCKS;
        int bi = 0, rem = mb;
        while (rem >= NT32 - bi) { rem -= NT32 - bi; ++bi; }
        const int bj = bi + rem;
        const int r0 = bi * 64;
        const int c0 = bj * 64;

        const int c4 = tid & 15;
        const int rr = tid >> 4;
        #pragma unroll
        for (int p = 0; p < 4; ++p) {
            const int kr = p * 16 + rr;
            const float4 v = *reinterpret_cast<const float4*>(
                &ddi[(size_t)(c0 + kr) * D_DIM + r0 + c4 * 4]);
            tile[kr][c4 * 4 + 0] = v.x;
            tile[kr][c4 * 4 + 1] = v.y;
            tile[kr][c4 * 4 + 2] = v.z;
            tile[kr][c4 * 4 + 3] = v.w;
        }
        __syncthreads();

        const int lane = tid & 63;
        const int w    = tid >> 6;
        int cnt = 0;
        #pragma unroll
        for (int rr2 = 0; rr2 < 16; ++rr2) {
            const int li = w * 16 + rr2;
            const int gi = r0 + li;
            const int gj = c0 + lane;
            const float a  = ddi[(size_t)gi * D_DIM + c0 + lane];  // coalesced row read
            const float at = tile[lane][li];                       // ddi[gj][gi]
            const bool bit = (gi < gj) && (a > 0.f || at > 0.f);
            const unsigned long long word = __ballot(bit);
            if (lane == 0) mask64[(size_t)gi * MWORDS + bj] = word;
            cnt += bit ? 1 : 0;
        }
        #pragma unroll
        for (int off = 32; off > 0; off >>= 1) cnt += __shfl_down(cnt, off, 64);
        if (lane == 0) redi[w] = cnt;
        __syncthreads();
        if (tid == 0) partials[mb] = redi[0] + redi[1] + redi[2] + redi[3];
    }
}

// Read one 32-byte (K=128-slice) MX-MFMA fragment from the XOR-swizzled LDS tile.
// Lane's 32 B = granules {2g, 2g+1} of row; swizzle maps them to slots {s, s^1}
// (adjacency preserved since XOR acts identically on both). 2x ds_read_b128, 2-way banks.
__device__ __forceinline__ i32x8 frag_read(const unsigned char* ls, int row, int g) {
    const int s = (2 * g) ^ (row & 7);
    const i32x4 lo = *reinterpret_cast<const i32x4*>(ls + row * BKB + s * 16);
    const i32x4 hi = *reinterpret_cast<const i32x4*>(ls + row * BKB + (s ^ 1) * 16);
    i32x8 r;
    r[0] = lo[0]; r[1] = lo[1]; r[2] = lo[2]; r[3] = lo[3];
    r[4] = hi[0]; r[5] = hi[1]; r[6] = hi[2]; r[7] = hi[3];
    return r;
}

// Gram = XT8_panel_i · XT8_panel_j^T, MX-scaled fp8 e4m3 with unit scales (e8m0=127),
// K=128 per MFMA instruction (4x fewer MFMA than 16x16x32 path; m148: 1.64x at this
// structure). 128x128 tile, 4 waves (2x2 of 64x64), single-buffered 32 KiB LDS,
// 2 barriers/K-step, gload16 staging with (row&7) 16B-granule XOR swizzle [rule #21].
// Grid 816 = 136 pairs x 6 K-splits, XCD-chunked bijective ordering (816 = 8 x 102).
__global__ __launch_bounds__(256) void gram_masked_kernel(
    const unsigned char* __restrict__ XT8,
    const unsigned long long* __restrict__ mask64,
    float* __restrict__ gsum)
{
    __shared__ __align__(16) unsigned char lsA[BMT * BKB];   // 16 KiB
    __shared__ __align__(16) unsigned char lsB[BMT * BKB];   // 16 KiB
    __shared__ float redf[4];

    const int tid  = threadIdx.x;
    const int lane = tid & 63;
    const int w    = tid >> 6;        // wave 0..3
    const int wr   = w >> 1, wc = w & 1;
    const int m16  = lane & 15;
    const int g    = lane >> 4;       // k-group 0..3 (32 B each of the 128 B row)

    const int bid = blockIdx.x;
    const int logical = (bid & 7) * (GRAM_BLOCKS / 8) + (bid >> 3);
    const int pair = logical / NSPL;          // ti-major pair order
    const int s    = logical % NSPL;

    int ti = 0, rem = pair;
    while (rem >= NTILE - ti) { rem -= NTILE - ti; ++ti; }
    const int tj = ti + rem;
    const int i0 = ti * BMT, j0 = tj * BMT;

    const int ks0 = (NKS * s) / NSPL;         // K-step range [ks0, ks1), 5-6 steps
    const int ks1 = (NKS * (s + 1)) / NSPL;
    const int nkt = ks1 - ks0;
    const int kbase = ks0 * BKB;              // byte offset into the 4096-byte K row

    f32x4 acc[4][4];
    #pragma unroll
    for (int a = 0; a < 4; ++a)
        #pragma unroll
        for (int b = 0; b < 4; ++b)
            acc[a][b] = (f32x4){0.f, 0.f, 0.f, 0.f};

    // Staging: chunk = p*256 + tid; 16B granules, row = chunk/8 (8 granules per 128 B row).
    // Linear LDS dest + inverse-swizzled global source: slot (row,c) gets granule (row, c^(row&7)).
    size_t gaoff[4], gboff[4];
    #pragma unroll
    for (int p = 0; p < 4; ++p) {
        const int chunk = p * 256 + tid;
        const int row = chunk >> 3;
        const int sc = (chunk & 7) ^ (row & 7);
        gaoff[p] = (size_t)(i0 + row) * B_DIM + kbase + sc * 16;
        gboff[p] = (size_t)(j0 + row) * B_DIM + kbase + sc * 16;
    }
    char* lbaseA = (char*)lsA + (size_t)w * 1024;   // wave-uniform segment base
    char* lbaseB = (char*)lsB + (size_t)w * 1024;

    for (int kt = 0; kt < nkt; ++kt) {
        const int koff = kt * BKB;
        #pragma unroll
        for (int p = 0; p < 4; ++p) {
            gload16(XT8 + gaoff[p] + koff, lbaseA + p * 4096);
            gload16(XT8 + gboff[p] + koff, lbaseB + p * 4096);
        }
        __syncthreads();   // drains vmcnt (LDS tiles ready)

        i32x8 aF[4], bF[4];
        #pragma unroll
        for (int f = 0; f < 4; ++f) {
            aF[f] = frag_read(lsA, wr * 64 + f * 16 + m16, g);
            bF[f] = frag_read(lsB, wc * 64 + f * 16 + m16, g);
        }
        #pragma unroll
        for (int fi = 0; fi < 4; ++fi)
            #pragma unroll
            for (int fj = 0; fj < 4; ++fj)
                acc[fi][fj] = __builtin_amdgcn_mfma_scale_f32_16x16x128_f8f6f4(
                    aF[fi], bF[fj], acc[fi][fj],
                    0 /*A fmt: fp8 e4m3*/, 0 /*B fmt: fp8 e4m3*/,
                    0, 0x7F7F7F7F /*A scales = 1.0*/,
                    0, 0x7F7F7F7F /*B scales = 1.0*/);

        __syncthreads();   // all waves done reading before next-stage overwrite
    }

    // Fused epilogue: masked sum from packed bits (mask encodes i<j already).
    // C/D layout: col = lane&15, row = (lane>>4)*4 + reg  [m89/m91; shape-determined]
    // Guard: words entirely below the diagonal are unwritten (poison) — skip them.
    float lsum = 0.f;
    const int jb = (j0 + wc * 64) >> 6;
    #pragma unroll
    for (int fi = 0; fi < 4; ++fi) {
        #pragma unroll
        for (int r = 0; r < 4; ++r) {
            const int i = i0 + wr * 64 + fi * 16 + g * 4 + r;
            unsigned long long wword = 0ull;
            if (jb * 64 + 63 > i) wword = mask64[(size_t)i * MWORDS + jb];
            #pragma unroll
            for (int fj = 0; fj < 4; ++fj) {
                if ((wword >> (fj * 16 + m16)) & 1ull) lsum += acc[fi][fj][r];
            }
        }
    }
    #pragma unroll
    for (int off = 32; off > 0; off >>= 1) lsum += __shfl_down(lsum, off, 64);
    if (lane == 0) redf[w] = lsum;
    __syncthreads();
    if (tid == 0) atomicAdd(gsum, redf[0] + redf[1] + redf[2] + redf[3]);
}

__global__ __launch_bounds__(256) void finalize_kernel(
    const float* __restrict__ gsum, const int* __restrict__ partials,
    float* __restrict__ out)
{
    __shared__ int redi[4];
    const int tid = threadIdx.x;
    int s = 0;
    for (int i = tid; i < MPAIR; i += 256) s += partials[i];
    #pragma unroll
    for (int off = 32; off > 0; off >>= 1) s += __shfl_down(s, off, 64);
    const int lane = tid & 63, w = tid >> 6;
    if (lane == 0) redi[w] = s;
    __syncthreads();
    if (tid == 0) {
        const int cnt = redi[0] + redi[1] + redi[2] + redi[3];
        out[0] = gsum[0] / ((float)B_DIM * fmaxf((float)cnt, 1.0f));
    }
}

extern "C" void kernel_launch(void* const* d_in, const int* in_sizes, int n_in,
                              void* d_out, int out_size, void* d_ws, size_t ws_size,
                              hipStream_t stream) {
    const float* X   = (const float*)d_in[0];   // drug_probs (B_DIM x D_DIM)
    const float* ddi = (const float*)d_in[1];   // ddi_matrix (D_DIM x D_DIM)
    float* out = (float*)d_out;

    const size_t XT_BYTES   = (size_t)D_DIM * B_DIM;                                // 8 MiB fp8
    const size_t MASK_BYTES = (size_t)D_DIM * MWORDS * sizeof(unsigned long long);  // 512 KiB
    const size_t PART_BYTES = (size_t)MPAIR * sizeof(int);
    if (ws_size < XT_BYTES + MASK_BYTES + PART_BYTES + 16) return;

    unsigned char* XT8 = (unsigned char*)d_ws;
    unsigned long long* mask64 = (unsigned long long*)((char*)d_ws + XT_BYTES);
    int*   partials = (int*)((char*)d_ws + XT_BYTES + MASK_BYTES);
    float* gsum     = (float*)((char*)d_ws + XT_BYTES + MASK_BYTES + PART_BYTES);

    prep_kernel<<<TP_BLOCKS + MPAIR, 256, 0, stream>>>(X, ddi, XT8, mask64, partials, gsum);
    gram_masked_kernel<<<GRAM_BLOCKS, 256, 0, stream>>>(XT8, mask64, gsum);
    finalize_kernel<<<1, 256, 0, stream>>>(gsum, partials, out);
}